// Round 6
// baseline (88.412 us; speedup 1.0000x reference)
//
#include <hip/hip_runtime.h>
#include <math.h>

// Problem constants (B=8, N=M=4096, 3-D points, fp32)
#define BATCH   8
#define NPTS    4096
#define TOTAL   (BATCH * NPTS)        // 32768 points per array
#define THREADS 256
#define P       4                     // self points per thread (~48 VGPR -> 8 waves/SIMD)
#define TILE    (THREADS * P)         // 1024 self points per block
#define TILES   (TOTAL / TILE)        // 32 self-tiles per direction
#define CHUNKS  32                    // q-split per batch
#define CHUNK   (NPTS / CHUNKS)       // 128 q points staged in LDS per block
#define NBLOCK  (2 * TILES * CHUNKS)  // 2048 blocks (8/CU, 8 waves/SIMD)

typedef float v2f __attribute__((ext_vector_type(2)));

// ws layout: partial[(dir*CHUNKS + chunk)*TOTAL + si], 2*CHUNKS*TOTAL floats
// (8 MB). Every slot is written exactly once by its owning block -> no init,
// no atomics. Kernel-end release makes stores visible to reduce1.

// d(s,q) = ||s||^2 + ||q||^2 - 2 s.q
//        = [ fma(-2qx, sx, fma(-2qy, sy, fma(-2qz, sz, ||q||^2))) ] + ||s||^2
// Bracket minimized over q (2 q-points per v_pk_fma_f32, v_min3_f32
// accumulate); +||s||^2 and the 0-clamp commute with min (monotone rounding),
// so they're applied once per partial before the store.
__global__ __launch_bounds__(THREADS, 8)
void chamfer_kernel(const float* __restrict__ a1, const float* __restrict__ a2,
                    float* __restrict__ partial) {
    const int bid   = blockIdx.x;
    const int dir   = bid >> 10;          // / (TILES*CHUNKS)=1024
    const int r     = bid & 1023;
    const int tile  = r >> 5;             // 0..31
    const int chunk = r & 31;             // 0..31
    const int batch = tile >> 2;          // 4 tiles (of 1024) per batch of 4096

    const float* __restrict__ sraw = dir ? a2 : a1;
    const float* __restrict__ qraw = dir ? a1 : a2;

    // ---- stage q chunk into LDS as packed pairs:
    //      lA[j] = (-2x_{2j}, -2x_{2j+1}, -2y_{2j}, -2y_{2j+1})
    //      lB[j] = (-2z_{2j}, -2z_{2j+1}, ||q_{2j}||^2, ||q_{2j+1}||^2)
    __shared__ float4 lA[CHUNK / 2];
    __shared__ float4 lB[CHUNK / 2];
    if (threadIdx.x < CHUNK / 2) {
        const int j = threadIdx.x;
        const int p = batch * NPTS + chunk * CHUNK + 2 * j;
        const float* __restrict__ g = qraw + 3 * p;
        float x0 = g[0], y0 = g[1], z0 = g[2];
        float x1 = g[3], y1 = g[4], z1 = g[5];
        lA[j] = make_float4(-2.0f * x0, -2.0f * x1, -2.0f * y0, -2.0f * y1);
        lB[j] = make_float4(-2.0f * z0, -2.0f * z1,
                            fmaf(x0, x0, fmaf(y0, y0, z0 * z0)),
                            fmaf(x1, x1, fmaf(y1, y1, z1 * z1)));
    }

    // ---- self-point coefficients (P per thread, coalesced across threads) ----
    v2f xd[P], yd[P], zd[P];
    float sq[P];
    #pragma unroll
    for (int k = 0; k < P; k++) {
        int si = tile * TILE + k * THREADS + threadIdx.x;
        float x = sraw[3 * si + 0];
        float y = sraw[3 * si + 1];
        float z = sraw[3 * si + 2];
        xd[k] = (v2f){x, x};
        yd[k] = (v2f){y, y};
        zd[k] = (v2f){z, z};
        sq[k] = fmaf(x, x, fmaf(y, y, z * z));
    }
    __syncthreads();

    // ---- main loop: 2 q-points per iter (v_pk_fma_f32), P self points each.
    //      2 ds_read_b128 (uniform addr -> broadcast, conflict-free) +
    //      P*(3 v_pk_fma_f32 + 1 v_min3_f32) per iteration.
    float acc[P];
    #pragma unroll
    for (int k = 0; k < P; k++) acc[k] = __builtin_inff();

    #pragma unroll 4
    for (int j = 0; j < CHUNK / 2; j++) {
        float4 A  = lA[j];
        float4 Bv = lB[j];
        v2f ax = {A.x, A.y};
        v2f ay = {A.z, A.w};
        v2f az = {Bv.x, Bv.y};
        v2f aw = {Bv.z, Bv.w};
        #pragma unroll
        for (int k = 0; k < P; k++) {
            v2f d = __builtin_elementwise_fma(az, zd[k], aw);
            d = __builtin_elementwise_fma(ay, yd[k], d);
            d = __builtin_elementwise_fma(ax, xd[k], d);
            acc[k] = fminf(fminf(d.x, d.y), acc[k]);   // -> v_min3_f32
        }
    }

    // one owner block per (si, chunk): plain coalesced stores, no atomics
    float* __restrict__ prow = partial + (size_t)(dir * CHUNKS + chunk) * TOTAL;
    #pragma unroll
    for (int k = 0; k < P; k++) {
        int si = tile * TILE + k * THREADS + threadIdx.x;
        prow[si] = fmaxf(acc[k] + sq[k], 0.0f);
    }
}

// min over the CHUNKS partials per row, then sum everything * 1/TOTAL.
// 256 blocks x 256 threads = 65536 threads = one per (dir, si) row.
__global__ __launch_bounds__(THREADS)
void reduce1_kernel(const float* __restrict__ partial, float* __restrict__ out) {
    const int tid = blockIdx.x * THREADS + threadIdx.x;   // 0..2*TOTAL-1
    const int dir = tid >> 15;
    const int si  = tid & (TOTAL - 1);
    const float* __restrict__ col = partial + (size_t)dir * CHUNKS * TOTAL + si;
    float m = __builtin_inff();
    #pragma unroll
    for (int c = 0; c < CHUNKS; c += 2)   // coalesced: consecutive threads -> consecutive si
        m = fminf(fminf(col[c * TOTAL], col[(c + 1) * TOTAL]), m);  // v_min3
    float s = m;
    #pragma unroll
    for (int off = 32; off > 0; off >>= 1) s += __shfl_down(s, off, 64);
    __shared__ float wsum[4];
    if ((threadIdx.x & 63) == 0) wsum[threadIdx.x >> 6] = s;
    __syncthreads();
    if (threadIdx.x == 0) {
        float bsum = (wsum[0] + wsum[1]) + (wsum[2] + wsum[3]);
        atomicAdd(out, bsum * (1.0f / (float)TOTAL));
    }
}

extern "C" void kernel_launch(void* const* d_in, const int* in_sizes, int n_in,
                              void* d_out, int out_size, void* d_ws, size_t ws_size,
                              hipStream_t stream) {
    const float* a1 = (const float*)d_in[0];
    const float* a2 = (const float*)d_in[1];
    float* out = (float*)d_out;

    float* partial = (float*)d_ws;    // 2*CHUNKS*TOTAL floats = 8 MB

    hipMemsetAsync(out, 0, sizeof(float), stream);   // 4-byte accumulator init
    chamfer_kernel<<<NBLOCK, THREADS, 0, stream>>>(a1, a2, partial);
    reduce1_kernel<<<(2 * TOTAL) / THREADS, THREADS, 0, stream>>>(partial, out);
}

// Round 7
// 79.511 us; speedup vs baseline: 1.1119x; 1.1119x over previous
//
#include <hip/hip_runtime.h>
#include <math.h>

// Problem constants (B=8, N=M=4096, 3-D points, fp32)
#define BATCH   8
#define NPTS    4096
#define TOTAL   (BATCH * NPTS)        // 32768 points per array
#define THREADS 256
#define P       8                     // self points per thread (register blocking)
#define TILE    (THREADS * P)         // 2048 self points per block
#define TILES   (TOTAL / TILE)        // 16 self-tiles per direction
#define CHUNKS  32                    // q-split per batch
#define CHUNK   (NPTS / CHUNKS)       // 128 q points staged in LDS per block
#define NBLOCK  (2 * TILES * CHUNKS)  // 1024 blocks (4/CU)

// ws layout: [0, 2*TOTAL*4) dist — f32-bits-as-uint min accumulators.
// Initialized to 0xFFFFFFFF by hipMemsetAsync (UINT_MAX): any clamped
// (non-negative, finite) float bit-pattern wins the first atomicMin.

// d(s,q) = ||s||^2 + ||q||^2 - 2 s.q
//        = [ fma(-2qx, sx, fma(-2qy, sy, fma(-2qz, sz, ||q||^2))) ] + ||s||^2
// Bracket minimized over q with SCALAR v_fma_f32 chains (peak fp32 on CDNA4 is
// the scalar rate; v_pk_fma_f32 buys nothing and may be half-rate), two q per
// group merged into the accumulator with one v_min3_f32. +||s||^2 and the
// 0-clamp commute with min (monotone rounding), applied once at the end.
__global__ __launch_bounds__(THREADS)
void chamfer_kernel(const float* __restrict__ a1, const float* __restrict__ a2,
                    unsigned* __restrict__ dist) {
    const int bid   = blockIdx.x;
    const int dir   = bid >> 9;           // / (TILES*CHUNKS)=512
    const int r     = bid & 511;
    const int tile  = r >> 5;             // 0..15
    const int chunk = r & 31;             // 0..31
    const int batch = tile >> 1;          // 2 tiles (of 2048) per batch of 4096

    const float* __restrict__ sraw = dir ? a2 : a1;
    const float* __restrict__ qraw = dir ? a1 : a2;

    // ---- stage q chunk into LDS: lq[j] = (-2x_j, -2y_j, -2z_j, ||q_j||^2) ----
    __shared__ float4 lq[CHUNK];
    if (threadIdx.x < CHUNK) {
        const int p = batch * NPTS + chunk * CHUNK + threadIdx.x;
        const float* __restrict__ g = qraw + 3 * p;
        float x = g[0], y = g[1], z = g[2];
        lq[threadIdx.x] = make_float4(-2.0f * x, -2.0f * y, -2.0f * z,
                                      fmaf(x, x, fmaf(y, y, z * z)));
    }

    // ---- self-point coefficients (P per thread, coalesced across threads) ----
    float xs[P], ys[P], zs[P], sq[P];
    #pragma unroll
    for (int k = 0; k < P; k++) {
        int si = tile * TILE + k * THREADS + threadIdx.x;
        float x = sraw[3 * si + 0];
        float y = sraw[3 * si + 1];
        float z = sraw[3 * si + 2];
        xs[k] = x;
        ys[k] = y;
        zs[k] = z;
        sq[k] = fmaf(x, x, fmaf(y, y, z * z));
    }
    __syncthreads();

    // ---- main loop: 2 q-points per group, P self points each.
    //      2 ds_read_b128 (uniform addr -> broadcast, conflict-free) +
    //      P*(6 v_fma_f32 + 1 v_min3_f32) per group. 16 independent fma
    //      chains per group -> ample ILP.
    float acc[P];
    #pragma unroll
    for (int k = 0; k < P; k++) acc[k] = __builtin_inff();

    #pragma unroll 2
    for (int j = 0; j < CHUNK; j += 2) {
        float4 q0 = lq[j];
        float4 q1 = lq[j + 1];
        #pragma unroll
        for (int k = 0; k < P; k++) {
            float d0 = fmaf(q0.x, xs[k], fmaf(q0.y, ys[k], fmaf(q0.z, zs[k], q0.w)));
            float d1 = fmaf(q1.x, xs[k], fmaf(q1.y, ys[k], fmaf(q1.z, zs[k], q1.w)));
            acc[k] = fminf(fminf(d0, d1), acc[k]);   // -> v_min3_f32
        }
    }

    #pragma unroll
    for (int k = 0; k < P; k++) {
        int si = tile * TILE + k * THREADS + threadIdx.x;
        float dmin = fmaxf(acc[k] + sq[k], 0.0f);  // non-negative => uint order OK
        atomicMin(dist + dir * TOTAL + si, __float_as_uint(dmin));
    }
    // no fence/handshake: kernel boundary publishes the atomicMin results.
}

__global__ __launch_bounds__(1024)
void reduce_kernel(const float* __restrict__ dist, float* __restrict__ out) {
    // mean(dist1) + mean(dist2) = (sum of all 2*TOTAL mins) / TOTAL
    const float4* __restrict__ dv = (const float4*)dist;  // 16384 float4
    float s = 0.0f;
    #pragma unroll
    for (int i = 0; i < (2 * TOTAL / 4) / 1024; i++) {
        float4 v = dv[i * 1024 + threadIdx.x];
        s += (v.x + v.y) + (v.z + v.w);
    }
    #pragma unroll
    for (int off = 32; off > 0; off >>= 1) s += __shfl_down(s, off, 64);
    __shared__ float wsum[16];
    if ((threadIdx.x & 63) == 0) wsum[threadIdx.x >> 6] = s;
    __syncthreads();
    if (threadIdx.x < 16) {
        float v = wsum[threadIdx.x];
        #pragma unroll
        for (int off = 8; off > 0; off >>= 1) v += __shfl_down(v, off, 16);
        if (threadIdx.x == 0) out[0] = v * (1.0f / (float)TOTAL);
    }
}

extern "C" void kernel_launch(void* const* d_in, const int* in_sizes, int n_in,
                              void* d_out, int out_size, void* d_ws, size_t ws_size,
                              hipStream_t stream) {
    const float* a1 = (const float*)d_in[0];
    const float* a2 = (const float*)d_in[1];
    float* out = (float*)d_out;

    unsigned* dist = (unsigned*)d_ws;

    // 0xFF bytes == UINT_MAX per word -> valid atomicMin(uint) init
    hipMemsetAsync(dist, 0xFF, (size_t)2 * TOTAL * sizeof(unsigned), stream);
    chamfer_kernel<<<NBLOCK, THREADS, 0, stream>>>(a1, a2, dist);
    reduce_kernel<<<1, 1024, 0, stream>>>((const float*)dist, out);
}